// Round 1
// baseline (78.173 us; speedup 1.0000x reference)
//
#include <hip/hip_runtime.h>

// DivLoss: per-row F1-reward -> softmax(r/TAU) -> KL(q || p), mean over batch.
// Key identity: F1_i = 2*c_i / (T + i + 1) with c_i = inclusive cumsum(labels),
// T = row sum. Handles c==0 / T==0 cases exactly (gives 0).
// KL_row = W/Z - log Z,  Z = sum exp(s_i),  W = sum exp(s_i)*(s_i - log p_i),
// s_i = F1_i / TAU (no max-subtraction needed: s in [0, 1.18]).

constexpr int L = 4096;

__global__ __launch_bounds__(256) void row_kl_kernel(const float* __restrict__ p,
                                                     const int* __restrict__ labels,
                                                     float* __restrict__ row_out) {
    const int b = blockIdx.x;
    const int t = threadIdx.x;       // 0..255, 4 waves
    const int lane = t & 63;
    const int wv = t >> 6;

    const int4* lab4 = (const int4*)(labels + (size_t)b * L) + t * 4;
    const float4* p4 = (const float4*)(p + (size_t)b * L) + t * 4;

    // each thread: 16 contiguous elements [16t, 16t+16)
    int4 a0 = lab4[0], a1 = lab4[1], a2 = lab4[2], a3 = lab4[3];
    float4 q0 = p4[0], q1 = p4[1], q2 = p4[2], q3 = p4[3];

    int lv[16] = {a0.x, a0.y, a0.z, a0.w, a1.x, a1.y, a1.z, a1.w,
                  a2.x, a2.y, a2.z, a2.w, a3.x, a3.y, a3.z, a3.w};
    float pv[16] = {q0.x, q0.y, q0.z, q0.w, q1.x, q1.y, q1.z, q1.w,
                    q2.x, q2.y, q2.z, q2.w, q3.x, q3.y, q3.z, q3.w};

    int tsum = 0;
    #pragma unroll
    for (int j = 0; j < 16; ++j) tsum += lv[j];

    // wave64 inclusive scan of per-thread sums
    int inc = tsum;
    #pragma unroll
    for (int d = 1; d < 64; d <<= 1) {
        int n = __shfl_up(inc, d, 64);
        if (lane >= d) inc += n;
    }

    __shared__ int wsum[4];
    __shared__ float red[8];
    if (lane == 63) wsum[wv] = inc;
    __syncthreads();
    const int w0 = wsum[0], w1 = wsum[1], w2 = wsum[2], w3 = wsum[3];
    const int T = w0 + w1 + w2 + w3;                 // row total positives
    int run = (wv > 0 ? w0 : 0) + (wv > 1 ? w1 : 0) + (wv > 2 ? w2 : 0)
              + inc - tsum;                          // exclusive prefix for this thread

    const float K = 2.0f / 0.85f;                    // 2 / TAU
    float Zl = 0.f, Wl = 0.f;
    const int base = t * 16 + 1;                     // k = global index + 1
    #pragma unroll
    for (int j = 0; j < 16; ++j) {
        run += lv[j];                                // inclusive cumsum c_i
        float s = K * __fdividef((float)run, (float)(T + base + j));
        float e = __expf(s);
        Zl += e;
        Wl += e * (s - __logf(pv[j]));
    }

    // block reduce (Z, W)
    #pragma unroll
    for (int d = 32; d >= 1; d >>= 1) {
        Zl += __shfl_down(Zl, d, 64);
        Wl += __shfl_down(Wl, d, 64);
    }
    if (lane == 0) { red[wv] = Zl; red[4 + wv] = Wl; }
    __syncthreads();
    if (t == 0) {
        float Z = red[0] + red[1] + red[2] + red[3];
        float W = red[4] + red[5] + red[6] + red[7];
        row_out[b] = W / Z - __logf(Z);
    }
}

__global__ __launch_bounds__(256) void final_reduce_kernel(const float* __restrict__ row,
                                                           float* __restrict__ out, int B) {
    const int t = threadIdx.x;
    float v = 0.f;
    for (int i = t; i < B; i += 256) v += row[i];
    #pragma unroll
    for (int d = 32; d >= 1; d >>= 1) v += __shfl_down(v, d, 64);
    __shared__ float s[4];
    if ((t & 63) == 0) s[t >> 6] = v;
    __syncthreads();
    if (t == 0) out[0] = (s[0] + s[1] + s[2] + s[3]) / (float)B;
}

extern "C" void kernel_launch(void* const* d_in, const int* in_sizes, int n_in,
                              void* d_out, int out_size, void* d_ws, size_t ws_size,
                              hipStream_t stream) {
    const float* p = (const float*)d_in[0];      // (B, L, 1) fp32, row-normalized
    const int* labels = (const int*)d_in[1];     // (B, L) int32 in {0,1}
    const int B = in_sizes[1] / L;
    float* row = (float*)d_ws;                   // B floats of scratch

    row_kl_kernel<<<B, 256, 0, stream>>>(p, labels, row);
    final_reduce_kernel<<<1, 256, 0, stream>>>(row, (float*)d_out, B);
}